// Round 8
// baseline (317.666 us; speedup 1.0000x reference)
//
#include <hip/hip_runtime.h>
#include <cstdint>
#include <cstddef>

#define DM  1024
#define SEQ 2048
#define BATCH 4
#define NH  16
#define DH  64
#define QKS 2048   // row stride of fused QK projection buffer (Q at 0, K at 1024)

typedef __bf16 bf16_t;
typedef __bf16 bf16x8 __attribute__((ext_vector_type(8)));
typedef __bf16 bf16x4 __attribute__((ext_vector_type(4)));
typedef float  f32x4  __attribute__((ext_vector_type(4)));

#define MFMA16(a, b, c) __builtin_amdgcn_mfma_f32_16x16x32_bf16((a), (b), (c), 0, 0, 0)

#define CS 0.18033688f  // (1/sqrt(64)) * log2(e), folded into Q projection

// async global->LDS, 16B per lane; LDS dest is wave-uniform base + lane*16
#define ASYNC_COPY16(gsrc, ldst)                                                   \
  __builtin_amdgcn_global_load_lds(                                                \
      (__attribute__((address_space(1))) void*)(gsrc),                             \
      (__attribute__((address_space(3))) void*)(ldst), 16, 0, 0)

#define NCVT (3 * BATCH * SEQ * DM / 4 / 256)  // 24576 cvt blocks

// ---------- fused prep: fp32->bf16 for Q/K/V  +  W^T bf16 for all 4 weights
// WTall rows: [0,1024) W_Q^T, [1024,2048) W_K^T, [2048,3072) W_V^T, [3072,4096) W_O^T
__global__ __launch_bounds__(256) void prep_kernel(const float* __restrict__ Q,
                                                   const float* __restrict__ K,
                                                   const float* __restrict__ V,
                                                   const float* __restrict__ W0,
                                                   const float* __restrict__ W1,
                                                   const float* __restrict__ W2,
                                                   const float* __restrict__ W3,
                                                   bf16_t* __restrict__ Qb,
                                                   bf16_t* __restrict__ Kb,
                                                   bf16_t* __restrict__ Vb,
                                                   bf16_t* __restrict__ WTall) {
  __shared__ float tile[32][33];
  const int bid = blockIdx.x;
  if (bid < NCVT) {
    const int n4 = BATCH * SEQ * DM / 4;
    int i = bid * 256 + threadIdx.x;
    const float* src; bf16_t* dst; int j;
    if (i < n4)           { src = Q; dst = Qb; j = i; }
    else if (i < 2 * n4)  { src = K; dst = Kb; j = i - n4; }
    else                  { src = V; dst = Vb; j = i - 2 * n4; }
    float4 v = ((const float4*)src)[j];
    bf16x4 o;
    o[0] = (bf16_t)v.x; o[1] = (bf16_t)v.y; o[2] = (bf16_t)v.z; o[3] = (bf16_t)v.w;
    *(bf16x4*)(dst + (size_t)j * 4) = o;
    return;
  }
  const int wb = bid - NCVT;
  const int widx = wb >> 10, wid = wb & 1023;
  const float* W = (widx == 0) ? W0 : (widx == 1) ? W1 : (widx == 2) ? W2 : W3;
  bf16_t* WT = WTall + (size_t)widx * DM * DM;
  const int bn = wid & 31, bk = wid >> 5;
  const int tx = threadIdx.x & 31, ty = threadIdx.x >> 5;  // ty 0..7
#pragma unroll
  for (int r = 0; r < 4; ++r)
    tile[ty + r * 8][tx] = W[(size_t)(bk * 32 + ty + r * 8) * DM + bn * 32 + tx];
  __syncthreads();
#pragma unroll
  for (int r = 0; r < 4; ++r)
    WT[(size_t)(bn * 32 + ty + r * 8) * DM + bk * 32 + tx] = (bf16_t)tile[tx][ty + r * 8];
}

// ------------------------------ C[M,N] = A[M,K] * BT[N,K]^T  (bf16 in, MFMA)
// 128x128 tile, BK=32 double-buffered (one barrier/iter). 4 waves, 2x2 of 64x64.
// 1D grid, XCD-aware swizzle: bid&7 = XCD -> m-stripe of 8 m-tiles; m fast, n slow.
// A selected per n-segment (fused QKV projection); columns < qcols scaled by qscale.
// If Vtr != nullptr, blocks with n0 >= 2048 (V projection) write TRANSPOSED per
// head to Vtr[b,h,d,s] via an XOR-swizzled LDS transpose.
__global__ __launch_bounds__(256) void gemm_bt_kernel(const bf16_t* __restrict__ A0,
                                                      const bf16_t* __restrict__ A1,
                                                      const bf16_t* __restrict__ A2,
                                                      const bf16_t* __restrict__ BT,
                                                      bf16_t* __restrict__ C,
                                                      bf16_t* __restrict__ Vtr,
                                                      int K, int ldc,
                                                      float qscale, int qcols) {
  __shared__ bf16_t Sh[4][128 * 32];  // [0..1]=A dbuf, [2..3]=B dbuf (32 KB)
  const int tid = threadIdx.x;
  const int wv = tid >> 6, lane = tid & 63;
  const int lo = lane & 15, quad = lane >> 4;

  const int bid = blockIdx.x;
  const int xcd = bid & 7;
  const int rid = bid >> 3;
  const int m0 = (xcd * 8 + (rid & 7)) * 128;
  const int n0 = (rid >> 3) * 128;
  const int wm = wv & 1, wn = wv >> 1;

  const bf16_t* A = (n0 < 1024) ? A0 : (n0 < 2048) ? A1 : A2;
  const float sc = (n0 < qcols) ? qscale : 1.0f;

  f32x4 acc[4][4] = {};

  const int srow = wv * 32 + (lane >> 2);
  const int scol = (lane & 3) * 8;
  const bf16_t* Ag = A + (size_t)(m0 + srow) * K + scol;
  const bf16_t* Bg = BT + (size_t)(n0 + srow) * K + scol;
  const int lds_off = (wv * 32) * 32;  // wave-uniform staging base (elements)

  ASYNC_COPY16(Ag, Sh[0] + lds_off);
  ASYNC_COPY16(Ag + (size_t)16 * K, Sh[0] + lds_off + 16 * 32);
  ASYNC_COPY16(Bg, Sh[2] + lds_off);
  ASYNC_COPY16(Bg + (size_t)16 * K, Sh[2] + lds_off + 16 * 32);

  const int kiters = K >> 5;
  for (int ki = 0; ki < kiters; ++ki) {
    const int cur = ki & 1;
    __syncthreads();  // drains cur's copies; prev readers of cur^1 done
    if (ki + 1 < kiters) {
      const int k1 = (ki + 1) << 5;
      ASYNC_COPY16(Ag + k1, Sh[cur ^ 1] + lds_off);
      ASYNC_COPY16(Ag + k1 + (size_t)16 * K, Sh[cur ^ 1] + lds_off + 16 * 32);
      ASYNC_COPY16(Bg + k1, Sh[2 + (cur ^ 1)] + lds_off);
      ASYNC_COPY16(Bg + k1 + (size_t)16 * K, Sh[2 + (cur ^ 1)] + lds_off + 16 * 32);
    }

    bf16x8 af[4], bfr[4];
#pragma unroll
    for (int t = 0; t < 4; ++t) {
      af[t]  = *(const bf16x8*)(Sh[cur] + (wm * 64 + t * 16 + lo) * 32 + quad * 8);
      bfr[t] = *(const bf16x8*)(Sh[2 + cur] + (wn * 64 + t * 16 + lo) * 32 + quad * 8);
    }
#pragma unroll
    for (int mt = 0; mt < 4; ++mt)
#pragma unroll
      for (int nt = 0; nt < 4; ++nt)
        acc[mt][nt] = MFMA16(af[mt], bfr[nt], acc[mt][nt]);
  }

  __syncthreads();  // all K-loop LDS reads done (epilogue may reuse Sh)

  if (Vtr != nullptr && n0 >= 2048) {
    // ---- V projection: transpose 64x64 per-wave subtile -> Vtr[b,h,d,s]
    bf16_t* Tw = &Sh[wv][0];  // 8 KB per-wave scratch
#pragma unroll
    for (int nt = 0; nt < 4; ++nt) {
      const int row = nt * 16 + lo;            // d
#pragma unroll
      for (int mt = 0; mt < 4; ++mt) {
        const int cb = mt * 16 + quad * 4;     // s base (4 consecutive)
        bf16x4 pk;
#pragma unroll
        for (int r = 0; r < 4; ++r) pk[r] = (bf16_t)acc[mt][nt][r];
        *(bf16x4*)(Tw + row * 64 + (((cb >> 3) ^ (row & 7)) * 8) + (cb & 7)) = pk;
      }
    }
    __asm__ volatile("s_waitcnt lgkmcnt(0)" ::: "memory");
    const int h  = ((n0 - 2048) >> 6) + wn;
    const int mg = m0 + wm * 64;
    const int b  = mg >> 11;                   // mg / SEQ
    const int s0 = mg & (SEQ - 1);
    const int dr = lane >> 3, ck = lane & 7;
    bf16_t* vbase = Vtr + ((size_t)((b * NH + h) * DH)) * SEQ + s0;
#pragma unroll
    for (int pass = 0; pass < 8; ++pass) {
      const int d = pass * 8 + dr;
      const bf16x8 vv = *(const bf16x8*)(Tw + d * 64 + ((ck ^ (d & 7)) * 8));
      *(bf16x8*)(vbase + (size_t)d * SEQ + ck * 8) = vv;
    }
    return;
  }

  // ---- normal epilogue: C/D layout col = lane&15, row = quad*4 + r
#pragma unroll
  for (int mt = 0; mt < 4; ++mt)
#pragma unroll
    for (int nt = 0; nt < 4; ++nt)
#pragma unroll
      for (int r = 0; r < 4; ++r) {
        const int m = m0 + wm * 64 + mt * 16 + quad * 4 + r;
        const int n = n0 + wn * 64 + nt * 16 + lo;
        C[(size_t)m * ldc + n] = (bf16_t)(acc[mt][nt][r] * sc);
      }
}

// -------------------------------------------- causal flash attention
// Block = 128 queries (4 waves x 32: two 16-q groups A/B per wave), Bc = 64.
// S^T = K*Q^T; each lane holds all 16 scores of ONE query per group. K and V
// frags are loaded from LDS once and feed both groups' MFMAs. Groups A/B SHARE
// one 2 KB per-wave P buffer (DS ops are in-order per wave: writePA->readPA->
// writePB->readPB is hazard-free) -> LDS = 40 KB -> 4 blocks/CU (R7's pairing
// starved TLP at 2 blocks/CU). Grid = 1024 blocks (all co-resident), qblk
// hi-lo interleaved for cross-CU balance. No max-tracking (log2-domain scores).
// K/V double-buffered; jt-loop unrolled x2 (iteration count 2q+2 is even).
__global__ __launch_bounds__(256, 4) void attn_kernel(const bf16_t* __restrict__ QKV,
                                                      const bf16_t* __restrict__ Vt,
                                                      bf16_t* __restrict__ ctx) {
  __shared__ bf16_t Ks[2][64 * 64];
  __shared__ bf16_t Vs[2][64 * 64];
  __shared__ bf16_t Ps[4][16 * 64];          // one 2 KB buffer per wave (shared A/B)
  const int tid = threadIdx.x;
  const int wv = tid >> 6, lane = tid & 63;
  const int lo = lane & 15, quad = lane >> 4;
  const int bh = blockIdx.x & 63;            // b*16 + h
  const int u16 = blockIdx.x >> 6;           // 0..15
  const int qblk = (u16 & 1) ? ((u16 - 1) >> 1) : (15 - (u16 >> 1));  // hi-lo mix
  const int b = bh >> 4, h = bh & 15;

  const bf16_t* Qg = QKV + ((size_t)b * SEQ) * QKS + h * DH;
  const bf16_t* Kg = QKV + ((size_t)b * SEQ) * QKS + 1024 + h * DH;
  const bf16_t* Vg = Vt + ((size_t)(bh * DH)) * SEQ;

  // staging map: unit U = (wv*2+i)*64 + lane -> LDS row U>>3, chunk U&7;
  // data there = global chunk (U&7)^(row&7)  (XOR swizzle)
  const int U0 = wv * 128 + lane, U1 = U0 + 64;
  const int r0 = U0 >> 3, cg0 = (U0 & 7) ^ (r0 & 7);
  const int r1 = U1 >> 3, cg1 = (U1 & 7) ^ (r1 & 7);

  bf16_t* Pw = &Ps[wv][0];
  const int pwr_base = lo * 64;
  const int prd0 = lo * 64 + ((quad ^ (lo & 7)) * 8);
  const int prd1 = lo * 64 + (((4 + quad) ^ (lo & 7)) * 8);

  const int jmax = 2 * qblk + 1;
  const int qw = qblk * 128 + wv * 16;       // group A row base
  const int qgA = qw + lo;
  const int qgB = qgA + 64;

  const bf16_t* Qba = Qg + ((size_t)qgA) * QKS + quad * 8;
  const bf16x8 aQ0A = *(const bf16x8*)(Qba);
  const bf16x8 aQ1A = *(const bf16x8*)(Qba + 32);
  const bf16_t* Qbb = Qba + (size_t)64 * QKS;
  const bf16x8 aQ0B = *(const bf16x8*)(Qbb);
  const bf16x8 aQ1B = *(const bf16x8*)(Qbb + 32);

  f32x4 OA[4] = {}, OB[4] = {};
  float lA = 0.0f, lB = 0.0f;

  // stage tile 0 into buffer 0
  ASYNC_COPY16(Kg + (size_t)r0 * QKS + cg0 * 8, Ks[0] + (wv * 2 + 0) * 512);
  ASYNC_COPY16(Kg + (size_t)r1 * QKS + cg1 * 8, Ks[0] + (wv * 2 + 1) * 512);
  ASYNC_COPY16(Vg + (size_t)r0 * SEQ + cg0 * 8, Vs[0] + (wv * 2 + 0) * 512);
  ASYNC_COPY16(Vg + (size_t)r1 * SEQ + cg1 * 8, Vs[0] + (wv * 2 + 1) * 512);

  for (int jtp = 0; jtp <= jmax; jtp += 2) {  // jmax odd -> even iter count
#pragma unroll
    for (int un = 0; un < 2; ++un) {          // un = buffer index (compile-time)
      const int jt = jtp + un;
      __syncthreads();  // drains tile jt's copies, syncs block
      if (jt < jmax) {
        const int j1 = (jt + 1) * 64;
        ASYNC_COPY16(Kg + (size_t)(j1 + r0) * QKS + cg0 * 8, Ks[un ^ 1] + (wv * 2 + 0) * 512);
        ASYNC_COPY16(Kg + (size_t)(j1 + r1) * QKS + cg1 * 8, Ks[un ^ 1] + (wv * 2 + 1) * 512);
        ASYNC_COPY16(Vg + (size_t)r0 * SEQ + j1 + cg0 * 8, Vs[un ^ 1] + (wv * 2 + 0) * 512);
        ASYNC_COPY16(Vg + (size_t)r1 * SEQ + j1 + cg1 * 8, Vs[un ^ 1] + (wv * 2 + 1) * 512);
      }

      const int j0 = jt * 64;
      const bool aact = (jt != jmax);         // group A skips the last tile
      const bool diagA = (jt == jmax - 1);
      const bool diagB = (jt == jmax);

      // QK: K frags loaded once, feed both groups
      f32x4 sA[4], sB[4];
#pragma unroll
      for (int mt = 0; mt < 4; ++mt) {
        const int row = mt * 16 + lo;
        const bf16x8 k0 = *(const bf16x8*)(Ks[un] + row * 64 + ((quad ^ (row & 7)) * 8));
        const bf16x8 k1 = *(const bf16x8*)(Ks[un] + row * 64 + (((4 + quad) ^ (row & 7)) * 8));
        if (aact) {
          f32x4 s = {};
          s = MFMA16(k0, aQ0A, s);
          s = MFMA16(k1, aQ1A, s);
          sA[mt] = s;
        }
        f32x4 t = {};
        t = MFMA16(k0, aQ0B, t);
        t = MFMA16(k1, aQ1B, t);
        sB[mt] = t;
      }

      // group A: exp2 + pack into P buffer
      if (aact) {
        float ls = 0.0f;
#pragma unroll
        for (int mt = 0; mt < 4; ++mt) {
          bf16x4 pk;
#pragma unroll
          for (int r = 0; r < 4; ++r) {
            float s = sA[mt][r];
            if (diagA && (j0 + mt * 16 + quad * 4 + r > qgA)) s = -1e30f;
            const float p = __builtin_amdgcn_exp2f(s);
            ls += p;
            pk[r] = (bf16_t)p;
          }
          const int sp = (mt * 2 + (quad >> 1)) ^ (lo & 7);
          *(bf16x4*)(Pw + pwr_base + sp * 8 + (quad & 1) * 4) = pk;
        }
        ls += __shfl_xor(ls, 16);
        ls += __shfl_xor(ls, 32);
        lA += ls;
      }

      // group B: exp2 to registers (hides PA roundtrip latency)
      bf16x4 pkB[4];
      {
        float ls = 0.0f;
#pragma unroll
        for (int mt = 0; mt < 4; ++mt) {
#pragma unroll
          for (int r = 0; r < 4; ++r) {
            float s = sB[mt][r];
            if (diagB && (j0 + mt * 16 + quad * 4 + r > qgB)) s = -1e30f;
            const float p = __builtin_amdgcn_exp2f(s);
            ls += p;
            pkB[mt][r] = (bf16_t)p;
          }
        }
        ls += __shfl_xor(ls, 16);
        ls += __shfl_xor(ls, 32);
        lB += ls;
      }

      // read PA (in-order DS per wave; explicit wait for data)
      bf16x8 pA0, pA1;
      if (aact) {
        __asm__ volatile("s_waitcnt lgkmcnt(0)" ::: "memory");
        pA0 = *(const bf16x8*)(Pw + prd0);
        pA1 = *(const bf16x8*)(Pw + prd1);
      }
      // write PB over the same buffer (WAR-safe: per-wave DS order)
#pragma unroll
      for (int mt = 0; mt < 4; ++mt) {
        const int sp = (mt * 2 + (quad >> 1)) ^ (lo & 7);
        *(bf16x4*)(Pw + pwr_base + sp * 8 + (quad & 1) * 4) = pkB[mt];
      }
      const bf16x8 pB0 = *(const bf16x8*)(Pw + prd0);
      const bf16x8 pB1 = *(const bf16x8*)(Pw + prd1);

      // PV: V frags loaded once, feed both groups
#pragma unroll
      for (int nt = 0; nt < 4; ++nt) {
        const int row = nt * 16 + lo;
        const bf16x8 v0 = *(const bf16x8*)(Vs[un] + row * 64 + ((quad ^ (row & 7)) * 8));
        const bf16x8 v1 = *(const bf16x8*)(Vs[un] + row * 64 + (((4 + quad) ^ (row & 7)) * 8));
        if (aact) {
          OA[nt] = MFMA16(pA0, v0, OA[nt]);
          OA[nt] = MFMA16(pA1, v1, OA[nt]);
        }
        OB[nt] = MFMA16(pB0, v0, OB[nt]);
        OB[nt] = MFMA16(pB1, v1, OB[nt]);
      }
    }
  }

  // final 1/l via shuffle; store (O C-layout: row q = quad*4+r, col d = nt*16+lo)
  float invA[4], invB[4];
#pragma unroll
  for (int r = 0; r < 4; ++r) {
    invA[r] = 1.0f / __shfl(lA, quad * 4 + r);
    invB[r] = 1.0f / __shfl(lB, quad * 4 + r);
  }
  bf16_t* outp = ctx + ((size_t)(b * SEQ + qw + quad * 4)) * DM + h * DH + lo;
#pragma unroll
  for (int r = 0; r < 4; ++r)
#pragma unroll
    for (int nt = 0; nt < 4; ++nt) {
      outp[(size_t)r * DM + nt * 16] = (bf16_t)(OA[nt][r] * invA[r]);
      outp[(size_t)(r + 64) * DM + nt * 16] = (bf16_t)(OB[nt][r] * invB[r]);
    }
}

// -------------------------------- residual + LayerNorm (Y in bf16, rest fp32)
__global__ __launch_bounds__(256) void ln_kernel(const float* __restrict__ Qin,
                                                 const bf16_t* __restrict__ Y,
                                                 const float* __restrict__ gamma,
                                                 const float* __restrict__ beta,
                                                 float* __restrict__ out) {
  const int row = blockIdx.x, t = threadIdx.x;
  const float4 a = ((const float4*)(Qin + (size_t)row * DM))[t];
  const bf16x4 yv = ((const bf16x4*)(Y + (size_t)row * DM))[t];
  const float x0 = a.x + (float)yv[0], x1 = a.y + (float)yv[1];
  const float x2 = a.z + (float)yv[2], x3 = a.w + (float)yv[3];
  float s  = x0 + x1 + x2 + x3;
  float ss = x0 * x0 + x1 * x1 + x2 * x2 + x3 * x3;
#pragma unroll
  for (int off = 1; off < 64; off <<= 1) { s += __shfl_xor(s, off); ss += __shfl_xor(ss, off); }
  __shared__ float red[8];
  const int wv = t >> 6, lane = t & 63;
  if (lane == 0) { red[wv * 2] = s; red[wv * 2 + 1] = ss; }
  __syncthreads();
  s  = red[0] + red[2] + red[4] + red[6];
  ss = red[1] + red[3] + red[5] + red[7];
  const float mu  = s * (1.0f / DM);
  const float var = ss * (1.0f / DM) - mu * mu;
  const float rstd = rsqrtf(var + 1e-5f);
  const float4 g  = ((const float4*)gamma)[t];
  const float4 be = ((const float4*)beta)[t];
  float4 o;
  o.x = (x0 - mu) * rstd * g.x + be.x;
  o.y = (x1 - mu) * rstd * g.y + be.y;
  o.z = (x2 - mu) * rstd * g.z + be.z;
  o.w = (x3 - mu) * rstd * g.w + be.w;
  ((float4*)(out + (size_t)row * DM))[t] = o;
}

// =============================================================================
extern "C" void kernel_launch(void* const* d_in, const int* in_sizes, int n_in,
                              void* d_out, int out_size, void* d_ws, size_t ws_size,
                              hipStream_t stream) {
  const float* Q     = (const float*)d_in[0];
  const float* K     = (const float*)d_in[1];
  const float* V     = (const float*)d_in[2];
  const float* W_Q   = (const float*)d_in[3];
  const float* W_K   = (const float*)d_in[4];
  const float* W_V   = (const float*)d_in[5];
  const float* W_O   = (const float*)d_in[6];
  const float* gamma = (const float*)d_in[7];
  const float* beta  = (const float*)d_in[8];
  float* out = (float*)d_out;

  char* ws = (char*)d_ws;
  const size_t SZB = (size_t)BATCH * SEQ * DM * 2;  // 16.78 MB (bf16 [8192,1024])
  const size_t WTB = (size_t)DM * DM * 2;           // 2 MB
  bf16_t* Qb    = (bf16_t*)(ws);                     // dead after QKV projection
  bf16_t* Kb    = (bf16_t*)(ws + SZB);
  bf16_t* Vb    = (bf16_t*)(ws + 2 * SZB);
  bf16_t* Yb    = (bf16_t*)(ws);                     // aliases Qb (16.8 MB, bf16 Y)
  bf16_t* WTall = (bf16_t*)(ws + 3 * SZB);           // 8.4 MB (4 weights ^T)
  char* p2 = ws + 3 * SZB + 4 * WTB;
  bf16_t* QKV = (bf16_t*)(p2);                       // [8192,2048] = 33.5 MB (Q|K)
  bf16_t* Vtr = (bf16_t*)(p2 + 2 * SZB);             // [64,64,2048] = 16.8 MB
  bf16_t* ctx = (bf16_t*)(p2 + 3 * SZB);             // [8192,1024] = 16.8 MB

  prep_kernel<<<NCVT + 4096, 256, 0, stream>>>(Q, K, V, W_Q, W_K, W_V, W_O,
                                               Qb, Kb, Vb, WTall);

  // fused QKV projection: C[:,0:1024]=Qb*WQ^T*CS, C[:,1024:2048]=Kb*WK^T,
  // n0>=2048 (V part) -> written transposed straight into Vtr
  gemm_bt_kernel<<<(3072 / 128) * (BATCH * SEQ / 128), 256, 0, stream>>>(
      Qb, Kb, Vb, WTall, QKV, Vtr, DM, QKS, CS, 1024);

  // 64 bh * 16 q-blocks of 128 queries; all 1024 blocks co-resident (4/CU)
  attn_kernel<<<64 * 16, 256, 0, stream>>>(QKV, Vtr, ctx);

  gemm_bt_kernel<<<(DM / 128) * (BATCH * SEQ / 128), 256, 0, stream>>>(
      ctx, ctx, ctx, WTall + (size_t)3 * DM * DM, Yb, nullptr, DM, DM, 1.0f, 0);
  ln_kernel<<<BATCH * SEQ, 256, 0, stream>>>(Q, Yb, gamma, beta, out);
}

// Round 9
// 307.266 us; speedup vs baseline: 1.0338x; 1.0338x over previous
//
#include <hip/hip_runtime.h>
#include <cstdint>
#include <cstddef>

#define DM  1024
#define SEQ 2048
#define BATCH 4
#define NH  16
#define DH  64
#define QKS 2048   // row stride of fused QK projection buffer (Q at 0, K at 1024)

typedef __bf16 bf16_t;
typedef __bf16 bf16x8 __attribute__((ext_vector_type(8)));
typedef __bf16 bf16x4 __attribute__((ext_vector_type(4)));
typedef float  f32x4  __attribute__((ext_vector_type(4)));

#define MFMA16(a, b, c) __builtin_amdgcn_mfma_f32_16x16x32_bf16((a), (b), (c), 0, 0, 0)

#define CS 0.18033688f  // (1/sqrt(64)) * log2(e), folded into Q projection

// async global->LDS, 16B per lane; LDS dest is wave-uniform base + lane*16
#define ASYNC_COPY16(gsrc, ldst)                                                   \
  __builtin_amdgcn_global_load_lds(                                                \
      (__attribute__((address_space(1))) void*)(gsrc),                             \
      (__attribute__((address_space(3))) void*)(ldst), 16, 0, 0)

#define NCVT (3 * BATCH * SEQ * DM / 4 / 256)  // 24576 cvt blocks

// ---------- fused prep: fp32->bf16 for Q/K/V  +  W^T bf16 for all 4 weights
// WTall rows: [0,1024) W_Q^T, [1024,2048) W_K^T, [2048,3072) W_V^T, [3072,4096) W_O^T
__global__ __launch_bounds__(256) void prep_kernel(const float* __restrict__ Q,
                                                   const float* __restrict__ K,
                                                   const float* __restrict__ V,
                                                   const float* __restrict__ W0,
                                                   const float* __restrict__ W1,
                                                   const float* __restrict__ W2,
                                                   const float* __restrict__ W3,
                                                   bf16_t* __restrict__ Qb,
                                                   bf16_t* __restrict__ Kb,
                                                   bf16_t* __restrict__ Vb,
                                                   bf16_t* __restrict__ WTall) {
  __shared__ float tile[32][33];
  const int bid = blockIdx.x;
  if (bid < NCVT) {
    const int n4 = BATCH * SEQ * DM / 4;
    int i = bid * 256 + threadIdx.x;
    const float* src; bf16_t* dst; int j;
    if (i < n4)           { src = Q; dst = Qb; j = i; }
    else if (i < 2 * n4)  { src = K; dst = Kb; j = i - n4; }
    else                  { src = V; dst = Vb; j = i - 2 * n4; }
    float4 v = ((const float4*)src)[j];
    bf16x4 o;
    o[0] = (bf16_t)v.x; o[1] = (bf16_t)v.y; o[2] = (bf16_t)v.z; o[3] = (bf16_t)v.w;
    *(bf16x4*)(dst + (size_t)j * 4) = o;
    return;
  }
  const int wb = bid - NCVT;
  const int widx = wb >> 10, wid = wb & 1023;
  const float* W = (widx == 0) ? W0 : (widx == 1) ? W1 : (widx == 2) ? W2 : W3;
  bf16_t* WT = WTall + (size_t)widx * DM * DM;
  const int bn = wid & 31, bk = wid >> 5;
  const int tx = threadIdx.x & 31, ty = threadIdx.x >> 5;  // ty 0..7
#pragma unroll
  for (int r = 0; r < 4; ++r)
    tile[ty + r * 8][tx] = W[(size_t)(bk * 32 + ty + r * 8) * DM + bn * 32 + tx];
  __syncthreads();
#pragma unroll
  for (int r = 0; r < 4; ++r)
    WT[(size_t)(bn * 32 + ty + r * 8) * DM + bk * 32 + tx] = (bf16_t)tile[tx][ty + r * 8];
}

// ------------------------------ C[M,N] = A[M,K] * BT[N,K]^T  (bf16 in, MFMA)
// 128x128 tile, BK=32 double-buffered (one barrier/iter). 4 waves, 2x2 of 64x64.
// 1D grid, XCD-aware swizzle: bid&7 = XCD -> m-stripe of 8 m-tiles; m fast, n slow.
// A selected per n-segment (fused QKV projection); columns < qcols scaled by qscale.
// If Vtr != nullptr, blocks with n0 >= 2048 (V projection) write TRANSPOSED per
// head to Vtr[b,h,d,s] via an XOR-swizzled LDS transpose.
__global__ __launch_bounds__(256) void gemm_bt_kernel(const bf16_t* __restrict__ A0,
                                                      const bf16_t* __restrict__ A1,
                                                      const bf16_t* __restrict__ A2,
                                                      const bf16_t* __restrict__ BT,
                                                      bf16_t* __restrict__ C,
                                                      bf16_t* __restrict__ Vtr,
                                                      int K, int ldc,
                                                      float qscale, int qcols) {
  __shared__ bf16_t Sh[4][128 * 32];  // [0..1]=A dbuf, [2..3]=B dbuf (32 KB)
  const int tid = threadIdx.x;
  const int wv = tid >> 6, lane = tid & 63;
  const int lo = lane & 15, quad = lane >> 4;

  const int bid = blockIdx.x;
  const int xcd = bid & 7;
  const int rid = bid >> 3;
  const int m0 = (xcd * 8 + (rid & 7)) * 128;
  const int n0 = (rid >> 3) * 128;
  const int wm = wv & 1, wn = wv >> 1;

  const bf16_t* A = (n0 < 1024) ? A0 : (n0 < 2048) ? A1 : A2;
  const float sc = (n0 < qcols) ? qscale : 1.0f;

  f32x4 acc[4][4] = {};

  const int srow = wv * 32 + (lane >> 2);
  const int scol = (lane & 3) * 8;
  const bf16_t* Ag = A + (size_t)(m0 + srow) * K + scol;
  const bf16_t* Bg = BT + (size_t)(n0 + srow) * K + scol;
  const int lds_off = (wv * 32) * 32;  // wave-uniform staging base (elements)

  ASYNC_COPY16(Ag, Sh[0] + lds_off);
  ASYNC_COPY16(Ag + (size_t)16 * K, Sh[0] + lds_off + 16 * 32);
  ASYNC_COPY16(Bg, Sh[2] + lds_off);
  ASYNC_COPY16(Bg + (size_t)16 * K, Sh[2] + lds_off + 16 * 32);

  const int kiters = K >> 5;
  for (int ki = 0; ki < kiters; ++ki) {
    const int cur = ki & 1;
    __syncthreads();  // drains cur's copies; prev readers of cur^1 done
    if (ki + 1 < kiters) {
      const int k1 = (ki + 1) << 5;
      ASYNC_COPY16(Ag + k1, Sh[cur ^ 1] + lds_off);
      ASYNC_COPY16(Ag + k1 + (size_t)16 * K, Sh[cur ^ 1] + lds_off + 16 * 32);
      ASYNC_COPY16(Bg + k1, Sh[2 + (cur ^ 1)] + lds_off);
      ASYNC_COPY16(Bg + k1 + (size_t)16 * K, Sh[2 + (cur ^ 1)] + lds_off + 16 * 32);
    }

    bf16x8 af[4], bfr[4];
#pragma unroll
    for (int t = 0; t < 4; ++t) {
      af[t]  = *(const bf16x8*)(Sh[cur] + (wm * 64 + t * 16 + lo) * 32 + quad * 8);
      bfr[t] = *(const bf16x8*)(Sh[2 + cur] + (wn * 64 + t * 16 + lo) * 32 + quad * 8);
    }
#pragma unroll
    for (int mt = 0; mt < 4; ++mt)
#pragma unroll
      for (int nt = 0; nt < 4; ++nt)
        acc[mt][nt] = MFMA16(af[mt], bfr[nt], acc[mt][nt]);
  }

  __syncthreads();  // all K-loop LDS reads done (epilogue may reuse Sh)

  if (Vtr != nullptr && n0 >= 2048) {
    // ---- V projection: transpose 64x64 per-wave subtile -> Vtr[b,h,d,s]
    bf16_t* Tw = &Sh[wv][0];  // 8 KB per-wave scratch
#pragma unroll
    for (int nt = 0; nt < 4; ++nt) {
      const int row = nt * 16 + lo;            // d
#pragma unroll
      for (int mt = 0; mt < 4; ++mt) {
        const int cb = mt * 16 + quad * 4;     // s base (4 consecutive)
        bf16x4 pk;
#pragma unroll
        for (int r = 0; r < 4; ++r) pk[r] = (bf16_t)acc[mt][nt][r];
        *(bf16x4*)(Tw + row * 64 + (((cb >> 3) ^ (row & 7)) * 8) + (cb & 7)) = pk;
      }
    }
    __asm__ volatile("s_waitcnt lgkmcnt(0)" ::: "memory");
    const int h  = ((n0 - 2048) >> 6) + wn;
    const int mg = m0 + wm * 64;
    const int b  = mg >> 11;                   // mg / SEQ
    const int s0 = mg & (SEQ - 1);
    const int dr = lane >> 3, ck = lane & 7;
    bf16_t* vbase = Vtr + ((size_t)((b * NH + h) * DH)) * SEQ + s0;
#pragma unroll
    for (int pass = 0; pass < 8; ++pass) {
      const int d = pass * 8 + dr;
      const bf16x8 vv = *(const bf16x8*)(Tw + d * 64 + ((ck ^ (d & 7)) * 8));
      *(bf16x8*)(vbase + (size_t)d * SEQ + ck * 8) = vv;
    }
    return;
  }

  // ---- normal epilogue: C/D layout col = lane&15, row = quad*4 + r
#pragma unroll
  for (int mt = 0; mt < 4; ++mt)
#pragma unroll
    for (int nt = 0; nt < 4; ++nt)
#pragma unroll
      for (int r = 0; r < 4; ++r) {
        const int m = m0 + wm * 64 + mt * 16 + quad * 4 + r;
        const int n = n0 + wn * 64 + nt * 16 + lo;
        C[(size_t)m * ldc + n] = (bf16_t)(acc[mt][nt][r] * sc);
      }
}

// -------------------------------------------- causal flash attention
// Block = 128 queries (4 waves x 32: two 16-q groups A/B per wave), Bc = 64.
// S^T = K*Q^T; each lane holds all 16 scores of ONE query per group. K and V
// frags are loaded from LDS once and feed both groups' MFMAs. Groups A/B share
// one 2 KB per-wave P buffer (per-wave DS ordering makes writePA->readPA->
// writePB->readPB hazard-free). LDS = 40 KB -> 4 blocks/CU.
// LOAD BALANCE (R8 post-mortem): co-scheduled blocks are bid stride-256 apart
// (u16 stride 4). Map u16=(j*4+i) -> qblk {15-i, 8+i, 7-i, i} so every class
// {i,i+4,i+8,i+12} sums to 30 q-blocks = 68 tiles -> every CU gets equal work,
// and its 4 blocks share the same (b,h) -> K/V L2 reuse.
__global__ __launch_bounds__(256, 4) void attn_kernel(const bf16_t* __restrict__ QKV,
                                                      const bf16_t* __restrict__ Vt,
                                                      bf16_t* __restrict__ ctx) {
  __shared__ bf16_t Ks[2][64 * 64];
  __shared__ bf16_t Vs[2][64 * 64];
  __shared__ bf16_t Ps[4][16 * 64];          // one 2 KB buffer per wave (shared A/B)
  const int tid = threadIdx.x;
  const int wv = tid >> 6, lane = tid & 63;
  const int lo = lane & 15, quad = lane >> 4;
  const int bh = blockIdx.x & 63;            // b*16 + h
  const int u16 = blockIdx.x >> 6;           // 0..15
  const int ci = u16 & 3, cj = u16 >> 2;
  const int qblk = (cj == 0) ? (15 - ci) : (cj == 1) ? (8 + ci)
                 : (cj == 2) ? (7 - ci) : ci;  // stride-4-class balanced
  const int b = bh >> 4, h = bh & 15;

  const bf16_t* Qg = QKV + ((size_t)b * SEQ) * QKS + h * DH;
  const bf16_t* Kg = QKV + ((size_t)b * SEQ) * QKS + 1024 + h * DH;
  const bf16_t* Vg = Vt + ((size_t)(bh * DH)) * SEQ;

  // staging map: unit U = (wv*2+i)*64 + lane -> LDS row U>>3, chunk U&7;
  // data there = global chunk (U&7)^(row&7)  (XOR swizzle)
  const int U0 = wv * 128 + lane, U1 = U0 + 64;
  const int r0 = U0 >> 3, cg0 = (U0 & 7) ^ (r0 & 7);
  const int r1 = U1 >> 3, cg1 = (U1 & 7) ^ (r1 & 7);

  bf16_t* Pw = &Ps[wv][0];
  const int pwr_base = lo * 64;
  const int prd0 = lo * 64 + ((quad ^ (lo & 7)) * 8);
  const int prd1 = lo * 64 + (((4 + quad) ^ (lo & 7)) * 8);

  const int jmax = 2 * qblk + 1;
  const int qw = qblk * 128 + wv * 16;       // group A row base
  const int qgA = qw + lo;
  const int qgB = qgA + 64;

  const bf16_t* Qba = Qg + ((size_t)qgA) * QKS + quad * 8;
  const bf16x8 aQ0A = *(const bf16x8*)(Qba);
  const bf16x8 aQ1A = *(const bf16x8*)(Qba + 32);
  const bf16_t* Qbb = Qba + (size_t)64 * QKS;
  const bf16x8 aQ0B = *(const bf16x8*)(Qbb);
  const bf16x8 aQ1B = *(const bf16x8*)(Qbb + 32);

  f32x4 OA[4] = {}, OB[4] = {};
  float lA = 0.0f, lB = 0.0f;

  // stage tile 0 into buffer 0
  ASYNC_COPY16(Kg + (size_t)r0 * QKS + cg0 * 8, Ks[0] + (wv * 2 + 0) * 512);
  ASYNC_COPY16(Kg + (size_t)r1 * QKS + cg1 * 8, Ks[0] + (wv * 2 + 1) * 512);
  ASYNC_COPY16(Vg + (size_t)r0 * SEQ + cg0 * 8, Vs[0] + (wv * 2 + 0) * 512);
  ASYNC_COPY16(Vg + (size_t)r1 * SEQ + cg1 * 8, Vs[0] + (wv * 2 + 1) * 512);

  for (int jtp = 0; jtp <= jmax; jtp += 2) {  // jmax odd -> even iter count
#pragma unroll
    for (int un = 0; un < 2; ++un) {          // un = buffer index (compile-time)
      const int jt = jtp + un;
      __syncthreads();  // drains tile jt's copies, syncs block
      if (jt < jmax) {
        const int j1 = (jt + 1) * 64;
        ASYNC_COPY16(Kg + (size_t)(j1 + r0) * QKS + cg0 * 8, Ks[un ^ 1] + (wv * 2 + 0) * 512);
        ASYNC_COPY16(Kg + (size_t)(j1 + r1) * QKS + cg1 * 8, Ks[un ^ 1] + (wv * 2 + 1) * 512);
        ASYNC_COPY16(Vg + (size_t)r0 * SEQ + j1 + cg0 * 8, Vs[un ^ 1] + (wv * 2 + 0) * 512);
        ASYNC_COPY16(Vg + (size_t)r1 * SEQ + j1 + cg1 * 8, Vs[un ^ 1] + (wv * 2 + 1) * 512);
      }

      const int j0 = jt * 64;
      const bool aact = (jt != jmax);         // group A skips the last tile
      const bool diagA = (jt == jmax - 1);
      const bool diagB = (jt == jmax);

      // QK: K frags loaded once, feed both groups
      f32x4 sA[4], sB[4];
#pragma unroll
      for (int mt = 0; mt < 4; ++mt) {
        const int row = mt * 16 + lo;
        const bf16x8 k0 = *(const bf16x8*)(Ks[un] + row * 64 + ((quad ^ (row & 7)) * 8));
        const bf16x8 k1 = *(const bf16x8*)(Ks[un] + row * 64 + (((4 + quad) ^ (row & 7)) * 8));
        if (aact) {
          f32x4 s = {};
          s = MFMA16(k0, aQ0A, s);
          s = MFMA16(k1, aQ1A, s);
          sA[mt] = s;
        }
        f32x4 t = {};
        t = MFMA16(k0, aQ0B, t);
        t = MFMA16(k1, aQ1B, t);
        sB[mt] = t;
      }

      // group A: exp2 + pack into P buffer
      if (aact) {
        float ls = 0.0f;
#pragma unroll
        for (int mt = 0; mt < 4; ++mt) {
          bf16x4 pk;
#pragma unroll
          for (int r = 0; r < 4; ++r) {
            float s = sA[mt][r];
            if (diagA && (j0 + mt * 16 + quad * 4 + r > qgA)) s = -1e30f;
            const float p = __builtin_amdgcn_exp2f(s);
            ls += p;
            pk[r] = (bf16_t)p;
          }
          const int sp = (mt * 2 + (quad >> 1)) ^ (lo & 7);
          *(bf16x4*)(Pw + pwr_base + sp * 8 + (quad & 1) * 4) = pk;
        }
        ls += __shfl_xor(ls, 16);
        ls += __shfl_xor(ls, 32);
        lA += ls;
      }

      // group B: exp2 to registers (hides PA roundtrip latency)
      bf16x4 pkB[4];
      {
        float ls = 0.0f;
#pragma unroll
        for (int mt = 0; mt < 4; ++mt) {
#pragma unroll
          for (int r = 0; r < 4; ++r) {
            float s = sB[mt][r];
            if (diagB && (j0 + mt * 16 + quad * 4 + r > qgB)) s = -1e30f;
            const float p = __builtin_amdgcn_exp2f(s);
            ls += p;
            pkB[mt][r] = (bf16_t)p;
          }
        }
        ls += __shfl_xor(ls, 16);
        ls += __shfl_xor(ls, 32);
        lB += ls;
      }

      // read PA (in-order DS per wave; explicit wait for data)
      bf16x8 pA0, pA1;
      if (aact) {
        __asm__ volatile("s_waitcnt lgkmcnt(0)" ::: "memory");
        pA0 = *(const bf16x8*)(Pw + prd0);
        pA1 = *(const bf16x8*)(Pw + prd1);
      }
      // write PB over the same buffer (WAR-safe: per-wave DS order)
#pragma unroll
      for (int mt = 0; mt < 4; ++mt) {
        const int sp = (mt * 2 + (quad >> 1)) ^ (lo & 7);
        *(bf16x4*)(Pw + pwr_base + sp * 8 + (quad & 1) * 4) = pkB[mt];
      }
      const bf16x8 pB0 = *(const bf16x8*)(Pw + prd0);
      const bf16x8 pB1 = *(const bf16x8*)(Pw + prd1);

      // PV: V frags loaded once, feed both groups
#pragma unroll
      for (int nt = 0; nt < 4; ++nt) {
        const int row = nt * 16 + lo;
        const bf16x8 v0 = *(const bf16x8*)(Vs[un] + row * 64 + ((quad ^ (row & 7)) * 8));
        const bf16x8 v1 = *(const bf16x8*)(Vs[un] + row * 64 + (((4 + quad) ^ (row & 7)) * 8));
        if (aact) {
          OA[nt] = MFMA16(pA0, v0, OA[nt]);
          OA[nt] = MFMA16(pA1, v1, OA[nt]);
        }
        OB[nt] = MFMA16(pB0, v0, OB[nt]);
        OB[nt] = MFMA16(pB1, v1, OB[nt]);
      }
    }
  }

  // final 1/l via shuffle; store (O C-layout: row q = quad*4+r, col d = nt*16+lo)
  float invA[4], invB[4];
#pragma unroll
  for (int r = 0; r < 4; ++r) {
    invA[r] = 1.0f / __shfl(lA, quad * 4 + r);
    invB[r] = 1.0f / __shfl(lB, quad * 4 + r);
  }
  bf16_t* outp = ctx + ((size_t)(b * SEQ + qw + quad * 4)) * DM + h * DH + lo;
#pragma unroll
  for (int r = 0; r < 4; ++r)
#pragma unroll
    for (int nt = 0; nt < 4; ++nt) {
      outp[(size_t)r * DM + nt * 16] = (bf16_t)(OA[nt][r] * invA[r]);
      outp[(size_t)(r + 64) * DM + nt * 16] = (bf16_t)(OB[nt][r] * invB[r]);
    }
}

// -------------------------------- residual + LayerNorm (Y in bf16, rest fp32)
__global__ __launch_bounds__(256) void ln_kernel(const float* __restrict__ Qin,
                                                 const bf16_t* __restrict__ Y,
                                                 const float* __restrict__ gamma,
                                                 const float* __restrict__ beta,
                                                 float* __restrict__ out) {
  const int row = blockIdx.x, t = threadIdx.x;
  const float4 a = ((const float4*)(Qin + (size_t)row * DM))[t];
  const bf16x4 yv = ((const bf16x4*)(Y + (size_t)row * DM))[t];
  const float x0 = a.x + (float)yv[0], x1 = a.y + (float)yv[1];
  const float x2 = a.z + (float)yv[2], x3 = a.w + (float)yv[3];
  float s  = x0 + x1 + x2 + x3;
  float ss = x0 * x0 + x1 * x1 + x2 * x2 + x3 * x3;
#pragma unroll
  for (int off = 1; off < 64; off <<= 1) { s += __shfl_xor(s, off); ss += __shfl_xor(ss, off); }
  __shared__ float red[8];
  const int wv = t >> 6, lane = t & 63;
  if (lane == 0) { red[wv * 2] = s; red[wv * 2 + 1] = ss; }
  __syncthreads();
  s  = red[0] + red[2] + red[4] + red[6];
  ss = red[1] + red[3] + red[5] + red[7];
  const float mu  = s * (1.0f / DM);
  const float var = ss * (1.0f / DM) - mu * mu;
  const float rstd = rsqrtf(var + 1e-5f);
  const float4 g  = ((const float4*)gamma)[t];
  const float4 be = ((const float4*)beta)[t];
  float4 o;
  o.x = (x0 - mu) * rstd * g.x + be.x;
  o.y = (x1 - mu) * rstd * g.y + be.y;
  o.z = (x2 - mu) * rstd * g.z + be.z;
  o.w = (x3 - mu) * rstd * g.w + be.w;
  ((float4*)(out + (size_t)row * DM))[t] = o;
}

// =============================================================================
extern "C" void kernel_launch(void* const* d_in, const int* in_sizes, int n_in,
                              void* d_out, int out_size, void* d_ws, size_t ws_size,
                              hipStream_t stream) {
  const float* Q     = (const float*)d_in[0];
  const float* K     = (const float*)d_in[1];
  const float* V     = (const float*)d_in[2];
  const float* W_Q   = (const float*)d_in[3];
  const float* W_K   = (const float*)d_in[4];
  const float* W_V   = (const float*)d_in[5];
  const float* W_O   = (const float*)d_in[6];
  const float* gamma = (const float*)d_in[7];
  const float* beta  = (const float*)d_in[8];
  float* out = (float*)d_out;

  char* ws = (char*)d_ws;
  const size_t SZB = (size_t)BATCH * SEQ * DM * 2;  // 16.78 MB (bf16 [8192,1024])
  const size_t WTB = (size_t)DM * DM * 2;           // 2 MB
  bf16_t* Qb    = (bf16_t*)(ws);                     // dead after QKV projection
  bf16_t* Kb    = (bf16_t*)(ws + SZB);
  bf16_t* Vb    = (bf16_t*)(ws + 2 * SZB);
  bf16_t* Yb    = (bf16_t*)(ws);                     // aliases Qb (16.8 MB, bf16 Y)
  bf16_t* WTall = (bf16_t*)(ws + 3 * SZB);           // 8.4 MB (4 weights ^T)
  char* p2 = ws + 3 * SZB + 4 * WTB;
  bf16_t* QKV = (bf16_t*)(p2);                       // [8192,2048] = 33.5 MB (Q|K)
  bf16_t* Vtr = (bf16_t*)(p2 + 2 * SZB);             // [64,64,2048] = 16.8 MB
  bf16_t* ctx = (bf16_t*)(p2 + 3 * SZB);             // [8192,1024] = 16.8 MB

  prep_kernel<<<NCVT + 4096, 256, 0, stream>>>(Q, K, V, W_Q, W_K, W_V, W_O,
                                               Qb, Kb, Vb, WTall);

  // fused QKV projection: C[:,0:1024]=Qb*WQ^T*CS, C[:,1024:2048]=Kb*WK^T,
  // n0>=2048 (V part) -> written transposed straight into Vtr
  gemm_bt_kernel<<<(3072 / 128) * (BATCH * SEQ / 128), 256, 0, stream>>>(
      Qb, Kb, Vb, WTall, QKV, Vtr, DM, QKS, CS, 1024);

  // 64 bh * 16 q-blocks of 128 queries; all 1024 blocks co-resident (4/CU)
  attn_kernel<<<64 * 16, 256, 0, stream>>>(QKV, Vtr, ctx);

  gemm_bt_kernel<<<(DM / 128) * (BATCH * SEQ / 128), 256, 0, stream>>>(
      ctx, ctx, ctx, WTall + (size_t)3 * DM * DM, Yb, nullptr, DM, DM, 1.0f, 0);
  ln_kernel<<<BATCH * SEQ, 256, 0, stream>>>(Q, Yb, gamma, beta, out);
}